// Round 1
// baseline (362.979 us; speedup 1.0000x reference)
//
#include <hip/hip_runtime.h>

typedef __attribute__((ext_vector_type(8))) short bf16x8;
typedef __attribute__((ext_vector_type(4))) float f32x4;

#define MFMA16(a, b, c) __builtin_amdgcn_mfma_f32_16x16x32_bf16(a, b, c, 0, 0, 0)

__device__ inline short f2bf(float f) {
  union { float f; unsigned u; } v;
  v.f = f;
  unsigned r = v.u + 0x7FFF + ((v.u >> 16) & 1);
  return (short)(r >> 16);
}

// ---------------- convert fp32 -> bf16 (straight) ----------------
__global__ __launch_bounds__(256) void cvt_kernel(const float* __restrict__ src,
                                                  short* __restrict__ dst, int n) {
  int i = (blockIdx.x * 256 + threadIdx.x) * 4;
  if (i >= n) return;
  float4 f = *(const float4*)&src[i];
  short4 o;
  o.x = f2bf(f.x); o.y = f2bf(f.y); o.z = f2bf(f.z); o.w = f2bf(f.w);
  *(short4*)&dst[i] = o;
}

// ---------------- transpose + convert: src (R x C) fp32 -> dst (C x R) bf16 ----------------
__global__ __launch_bounds__(256) void tconv_kernel(const float* __restrict__ src,
                                                    short* __restrict__ dst, int R, int C) {
  __shared__ float t[32][33];
  const int bx = blockIdx.x * 32;  // col base in src
  const int by = blockIdx.y * 32;  // row base in src
  const int tx = threadIdx.x & 31;
  const int ty = threadIdx.x >> 5;  // 0..7
#pragma unroll
  for (int i = 0; i < 4; i++)
    t[ty + i * 8][tx] = src[(size_t)(by + ty + i * 8) * C + bx + tx];
  __syncthreads();
#pragma unroll
  for (int i = 0; i < 4; i++)
    dst[(size_t)(bx + ty + i * 8) * R + by + tx] = f2bf(t[tx][ty + i * 8]);
}

// ---------------- bf16 GEMM: C(MxN fp32) = A(MxK bf16) * B^T(NxK bf16) ----------------
// 128x128 tile, BK=32, 4 waves each 64x64 via 4x4 MFMA 16x16x32
__global__ __launch_bounds__(256) void gemm_kernel(const short* __restrict__ A,
                                                   const short* __restrict__ B,
                                                   float* __restrict__ C,
                                                   int M, int N, int K) {
  __shared__ __align__(16) short As[128 * 40];
  __shared__ __align__(16) short Bs[128 * 40];
  const int tid = threadIdx.x;
  const int lane = tid & 63, wave = tid >> 6;
  const int quad = lane >> 4, l16 = lane & 15;
  const int m0 = blockIdx.y * 128, n0 = blockIdx.x * 128;
  const int wm = (wave >> 1) * 64, wn = (wave & 1) * 64;
  f32x4 acc[4][4];
#pragma unroll
  for (int mi = 0; mi < 4; mi++)
#pragma unroll
    for (int ni = 0; ni < 4; ni++) acc[mi][ni] = (f32x4){0.f, 0.f, 0.f, 0.f};

  for (int k0 = 0; k0 < K; k0 += 32) {
#pragma unroll
    for (int i = 0; i < 2; i++) {
      int c = i * 256 + tid;       // 512 chunks of 8 bf16 per tile
      int row = c >> 2, cc = (c & 3) * 8;
      *(int4*)&As[row * 40 + cc] = *(const int4*)&A[(size_t)(m0 + row) * K + k0 + cc];
      *(int4*)&Bs[row * 40 + cc] = *(const int4*)&B[(size_t)(n0 + row) * K + k0 + cc];
    }
    __syncthreads();
    bf16x8 af[4], bfr[4];
#pragma unroll
    for (int mi = 0; mi < 4; mi++)
      af[mi] = *(const bf16x8*)&As[(wm + mi * 16 + l16) * 40 + quad * 8];
#pragma unroll
    for (int ni = 0; ni < 4; ni++)
      bfr[ni] = *(const bf16x8*)&Bs[(wn + ni * 16 + l16) * 40 + quad * 8];
#pragma unroll
    for (int mi = 0; mi < 4; mi++)
#pragma unroll
      for (int ni = 0; ni < 4; ni++)
        acc[mi][ni] = MFMA16(af[mi], bfr[ni], acc[mi][ni]);
    __syncthreads();
  }
#pragma unroll
  for (int mi = 0; mi < 4; mi++)
#pragma unroll
    for (int ni = 0; ni < 4; ni++)
#pragma unroll
      for (int r = 0; r < 4; r++)
        C[(size_t)(m0 + wm + mi * 16 + quad * 4 + r) * N + n0 + wn + ni * 16 + l16] =
            acc[mi][ni][r];
}

// ---------------- bias + rmsnorm + rope + mask + scatter ----------------
// grid (20 slots, B*S), block 128. slots: 0..15 q heads, 16..17 k kv-heads, 18..19 v kv-heads
__global__ __launch_bounds__(128) void qkv_post_kernel(
    const float* __restrict__ qkv, const float* __restrict__ qbias,
    const float* __restrict__ kbias, const float* __restrict__ vbias,
    const float* __restrict__ qg, const float* __restrict__ kg,
    const float* __restrict__ cosb, const float* __restrict__ sinb,
    const float* __restrict__ maskp, short* __restrict__ qo, short* __restrict__ ko,
    short* __restrict__ vo) {
  const int slot = blockIdx.x;
  const int bs = blockIdx.y;
  const int b = bs >> 10, s = bs & 1023;
  const int d = threadIdx.x;
  __shared__ float vals[128];
  __shared__ float red[2];
  const float* row = qkv + (size_t)bs * 2560;
  float val;
  if (slot < 16) {
    val = row[slot * 128 + d] + qbias[slot * 128 + d];
  } else if (slot < 18) {
    int kvh = slot - 16;
    val = row[2048 + kvh * 128 + d] + kbias[kvh * 128 + d];
  } else {
    int kvh = slot - 18;
    val = row[2304 + kvh * 128 + d] + vbias[kvh * 128 + d];
  }
  if (slot < 18) {
    // rmsnorm over 128
    float ss = val * val;
#pragma unroll
    for (int o = 1; o < 64; o <<= 1) ss += __shfl_xor(ss, o);
    if ((threadIdx.x & 63) == 0) red[threadIdx.x >> 6] = ss;
    __syncthreads();
    float var = (red[0] + red[1]) * (1.0f / 128.0f);
    float g = (slot < 16) ? qg[d] : kg[d];
    val = g * val * rsqrtf(var + 1e-6f);
    vals[d] = val;
    __syncthreads();
    float partner = (d < 64) ? -vals[d + 64] : vals[d - 64];
    // sectioned rope table select per _reorder: SEC=(16,24,24) twice
    int sel = (d < 16) ? 0 : (d < 40) ? 1 : (d < 64) ? 2 : (d < 80) ? 0 : (d < 104) ? 1 : 2;
    size_t ci = ((size_t)(sel * 2 + b) * 1024 + s) * 128 + d;
    val = val * cosb[ci] + partner * sinb[ci];
  }
  if (slot >= 16) val *= maskp[bs];
  short o16 = f2bf(val);
  if (slot < 16) {
    qo[(((size_t)(b * 16 + slot) * 1024) + s) * 128 + d] = o16;
  } else if (slot < 18) {
    ko[(((size_t)(b * 2 + (slot - 16)) * 1024) + s) * 128 + d] = o16;
  } else {
    vo[(((size_t)(b * 2 + (slot - 18)) * 1024) + s) * 128 + d] = o16;
  }
}

// ---------------- flash-style causal GQA attention ----------------
// grid (S/64, NH, B), block 256 (4 waves); wave handles 16 q rows; 32-key steps
__global__ __launch_bounds__(256) void attn_kernel(const short* __restrict__ Q,
                                                   const short* __restrict__ K,
                                                   const short* __restrict__ V,
                                                   short* __restrict__ Oo) {
  const int qt = blockIdx.x;
  const int h = blockIdx.y;
  const int b = blockIdx.z;
  const int kv = h >> 3;  // G = 8
  const int tid = threadIdx.x;
  const int wave = tid >> 6, lane = tid & 63;
  const int quad = lane >> 4, l16 = lane & 15;
  __shared__ __align__(16) short Ks[32 * 136];   // K-tile rows (key, d) pad->136
  __shared__ __align__(16) short Vt[128 * 40];   // V-tile transposed (d, key) pad->40
  __shared__ __align__(16) short Ps[4][16 * 40]; // per-wave P scratch (row, key) pad->40

  const size_t qoff = (((size_t)(b * 16 + h) * 1024) + qt * 64 + wave * 16 + l16) * 128;
  bf16x8 aq[4];
#pragma unroll
  for (int kk = 0; kk < 4; kk++) aq[kk] = *(const bf16x8*)&Q[qoff + kk * 32 + quad * 8];

  f32x4 o[8];
#pragma unroll
  for (int i = 0; i < 8; i++) o[i] = (f32x4){0.f, 0.f, 0.f, 0.f};
  float m[4], l[4];
#pragma unroll
  for (int r = 0; r < 4; r++) { m[r] = -1e30f; l[r] = 0.f; }
  const int qrow0 = qt * 64 + wave * 16 + quad * 4;
  const size_t kvoff = ((size_t)(b * 2 + kv) * 1024) * 128;
  const int nsteps = qt * 2 + 2;
  const float scale = 0.08838834764831845f;  // 1/sqrt(128)

  for (int st = 0; st < nsteps; st++) {
    const int ks0 = st * 32;
#pragma unroll
    for (int i = 0; i < 2; i++) {
      int c = i * 256 + tid;  // 512 chunks of 8
      int key = c >> 4, cc = (c & 15) * 8;
      *(int4*)&Ks[key * 136 + cc] = *(const int4*)&K[kvoff + (size_t)(ks0 + key) * 128 + cc];
      int4 vvec = *(const int4*)&V[kvoff + (size_t)(ks0 + key) * 128 + cc];
      const short* vs = (const short*)&vvec;
#pragma unroll
      for (int j = 0; j < 8; j++) Vt[(cc + j) * 40 + key] = vs[j];
    }
    __syncthreads();
    // scores: S(16q x 32k) = Q(16x128) . K^T
    f32x4 sc[2] = {(f32x4){0.f, 0.f, 0.f, 0.f}, (f32x4){0.f, 0.f, 0.f, 0.f}};
#pragma unroll
    for (int nt = 0; nt < 2; nt++)
#pragma unroll
      for (int kk = 0; kk < 4; kk++) {
        bf16x8 bk = *(const bf16x8*)&Ks[(nt * 16 + l16) * 136 + kk * 32 + quad * 8];
        sc[nt] = MFMA16(aq[kk], bk, sc[nt]);
      }
    float sv[2][4], mx[4];
#pragma unroll
    for (int r = 0; r < 4; r++) mx[r] = -1e30f;
#pragma unroll
    for (int nt = 0; nt < 2; nt++)
#pragma unroll
      for (int r = 0; r < 4; r++) {
        float s = sc[nt][r] * scale;
        int kcol = ks0 + nt * 16 + l16;
        if (kcol > qrow0 + r) s = -1e30f;  // causal
        sv[nt][r] = s;
        mx[r] = fmaxf(mx[r], s);
      }
#pragma unroll
    for (int off = 1; off < 16; off <<= 1)
#pragma unroll
      for (int r = 0; r < 4; r++) mx[r] = fmaxf(mx[r], __shfl_xor(mx[r], off));
    float alpha[4], rs[4];
#pragma unroll
    for (int r = 0; r < 4; r++) {
      float mn = fmaxf(m[r], mx[r]);
      alpha[r] = __expf(m[r] - mn);
      m[r] = mn;
      rs[r] = 0.f;
    }
#pragma unroll
    for (int nt = 0; nt < 2; nt++)
#pragma unroll
      for (int r = 0; r < 4; r++) {
        float p = __expf(sv[nt][r] - m[r]);
        sv[nt][r] = p;
        rs[r] += p;
      }
#pragma unroll
    for (int off = 1; off < 16; off <<= 1)
#pragma unroll
      for (int r = 0; r < 4; r++) rs[r] += __shfl_xor(rs[r], off);
#pragma unroll
    for (int r = 0; r < 4; r++) l[r] = l[r] * alpha[r] + rs[r];
#pragma unroll
    for (int i = 0; i < 8; i++)
#pragma unroll
      for (int r = 0; r < 4; r++) o[i][r] *= alpha[r];
    // P: C-layout -> A-layout via per-wave LDS round-trip
    short* P = &Ps[wave][0];
#pragma unroll
    for (int nt = 0; nt < 2; nt++)
#pragma unroll
      for (int r = 0; r < 4; r++)
        P[(quad * 4 + r) * 40 + nt * 16 + l16] = f2bf(sv[nt][r]);
    __asm__ volatile("s_waitcnt lgkmcnt(0)" ::: "memory");
    bf16x8 pa = *(const bf16x8*)&P[l16 * 40 + quad * 8];
#pragma unroll
    for (int nt = 0; nt < 8; nt++) {
      bf16x8 bv = *(const bf16x8*)&Vt[(nt * 16 + l16) * 40 + quad * 8];
      o[nt] = MFMA16(pa, bv, o[nt]);
    }
    __syncthreads();
  }
#pragma unroll
  for (int r = 0; r < 4; r++) l[r] = 1.f / l[r];
#pragma unroll
  for (int nt = 0; nt < 8; nt++)
#pragma unroll
    for (int r = 0; r < 4; r++) {
      size_t idx = ((size_t)(b * 1024 + qrow0 + r)) * 2048 + h * 128 + nt * 16 + l16;
      Oo[idx] = f2bf(o[nt][r] * l[r]);
    }
}

extern "C" void kernel_launch(void* const* d_in, const int* in_sizes, int n_in,
                              void* d_out, int out_size, void* d_ws, size_t ws_size,
                              hipStream_t stream) {
  const float* x = (const float*)d_in[0];
  const float* cosb = (const float*)d_in[1];
  const float* sinb = (const float*)d_in[2];
  const float* mask = (const float*)d_in[3];
  const float* q_w = (const float*)d_in[4];
  const float* q_b = (const float*)d_in[5];
  const float* k_w = (const float*)d_in[6];
  const float* k_b = (const float*)d_in[7];
  const float* v_w = (const float*)d_in[8];
  const float* v_b = (const float*)d_in[9];
  const float* qg = (const float*)d_in[10];
  const float* kg = (const float*)d_in[11];
  const float* o_w = (const float*)d_in[12];
  float* out = (float*)d_out;

  char* ws = (char*)d_ws;
  // region A (8MB): xb, later reused as attention output
  short* xb = (short*)(ws);
  short* attn = xb;
  // region B (10MB): concatenated N-major qkv weight (2560 x 2048)
  short* wqkv_t = (short*)(ws + (size_t)(8u << 20));
  // region C (20MB): fp32 qkv raw; first 8MB reused later as o_w^T bf16
  float* qkv_raw = (float*)(ws + (size_t)(18u << 20));
  short* wo_t = (short*)(ws + (size_t)(18u << 20));
  // regions D/E/F
  short* qb = (short*)(ws + (size_t)(38u << 20));  // 8 MB  (B,NH,S,HD)
  short* kb = (short*)(ws + (size_t)(46u << 20));  // 1 MB  (B,NKV,S,HD)
  short* vb = (short*)(ws + (size_t)(47u << 20));  // 1 MB
  // total 48 MB

  // 1. convert x -> bf16
  cvt_kernel<<<4096, 256, 0, stream>>>(x, xb, 2048 * 2048);
  // 2. transpose-convert weights into concatenated N-major (2560 x 2048)
  tconv_kernel<<<dim3(64, 64), 256, 0, stream>>>(q_w, wqkv_t, 2048, 2048);
  tconv_kernel<<<dim3(8, 64), 256, 0, stream>>>(k_w, wqkv_t + (size_t)2048 * 2048, 2048, 256);
  tconv_kernel<<<dim3(8, 64), 256, 0, stream>>>(v_w, wqkv_t + (size_t)2304 * 2048, 2048, 256);
  // 3. QKV GEMM: (2048 x 2560) fp32
  gemm_kernel<<<dim3(20, 16), 256, 0, stream>>>(xb, wqkv_t, qkv_raw, 2048, 2560, 2048);
  // 4. bias + rmsnorm + rope + mask + scatter to bf16
  qkv_post_kernel<<<dim3(20, 2048), 128, 0, stream>>>(qkv_raw, q_b, k_b, v_b, qg, kg, cosb,
                                                      sinb, mask, qb, kb, vb);
  // 5. transpose o_w (after qkv_raw is consumed; overlaps region C)
  tconv_kernel<<<dim3(64, 64), 256, 0, stream>>>(o_w, wo_t, 2048, 2048);
  // 6. attention
  attn_kernel<<<dim3(16, 16, 2), 256, 0, stream>>>(qb, kb, vb, attn);
  // 7. output GEMM -> d_out fp32
  gemm_kernel<<<dim3(16, 16), 256, 0, stream>>>(attn, wo_t, out, 2048, 2048, 2048);
}

// Round 2
// 311.468 us; speedup vs baseline: 1.1654x; 1.1654x over previous
//
#include <hip/hip_runtime.h>

typedef __attribute__((ext_vector_type(8))) short bf16x8;
typedef __attribute__((ext_vector_type(4))) float f32x4;

#define MFMA16(a, b, c) __builtin_amdgcn_mfma_f32_16x16x32_bf16(a, b, c, 0, 0, 0)

__device__ inline short f2bf(float f) {
  union { float f; unsigned u; } v;
  v.f = f;
  unsigned r = v.u + 0x7FFF + ((v.u >> 16) & 1);
  return (short)(r >> 16);
}

// ---------------- convert fp32 -> bf16 (straight) ----------------
__global__ __launch_bounds__(256) void cvt_kernel(const float* __restrict__ src,
                                                  short* __restrict__ dst, int n) {
  int i = (blockIdx.x * 256 + threadIdx.x) * 4;
  if (i >= n) return;
  float4 f = *(const float4*)&src[i];
  short4 o;
  o.x = f2bf(f.x); o.y = f2bf(f.y); o.z = f2bf(f.z); o.w = f2bf(f.w);
  *(short4*)&dst[i] = o;
}

// ---------------- transpose + convert: src (R x C) fp32 -> dst (C x R) bf16 ----------------
__global__ __launch_bounds__(256) void tconv_kernel(const float* __restrict__ src,
                                                    short* __restrict__ dst, int R, int C) {
  __shared__ float t[32][33];
  const int bx = blockIdx.x * 32;  // col base in src
  const int by = blockIdx.y * 32;  // row base in src
  const int tx = threadIdx.x & 31;
  const int ty = threadIdx.x >> 5;  // 0..7
#pragma unroll
  for (int i = 0; i < 4; i++)
    t[ty + i * 8][tx] = src[(size_t)(by + ty + i * 8) * C + bx + tx];
  __syncthreads();
#pragma unroll
  for (int i = 0; i < 4; i++)
    dst[(size_t)(bx + ty + i * 8) * R + by + tx] = f2bf(t[tx][ty + i * 8]);
}

// ---------------- bf16 GEMM: C(MxN fp32) = A(MxK bf16) * B^T(NxK bf16) ----------------
__global__ __launch_bounds__(256) void gemm_kernel(const short* __restrict__ A,
                                                   const short* __restrict__ B,
                                                   float* __restrict__ C,
                                                   int M, int N, int K) {
  __shared__ __align__(16) short As[128 * 40];
  __shared__ __align__(16) short Bs[128 * 40];
  const int tid = threadIdx.x;
  const int lane = tid & 63, wave = tid >> 6;
  const int quad = lane >> 4, l16 = lane & 15;
  const int m0 = blockIdx.y * 128, n0 = blockIdx.x * 128;
  const int wm = (wave >> 1) * 64, wn = (wave & 1) * 64;
  f32x4 acc[4][4];
#pragma unroll
  for (int mi = 0; mi < 4; mi++)
#pragma unroll
    for (int ni = 0; ni < 4; ni++) acc[mi][ni] = (f32x4){0.f, 0.f, 0.f, 0.f};

  for (int k0 = 0; k0 < K; k0 += 32) {
#pragma unroll
    for (int i = 0; i < 2; i++) {
      int c = i * 256 + tid;
      int row = c >> 2, cc = (c & 3) * 8;
      *(int4*)&As[row * 40 + cc] = *(const int4*)&A[(size_t)(m0 + row) * K + k0 + cc];
      *(int4*)&Bs[row * 40 + cc] = *(const int4*)&B[(size_t)(n0 + row) * K + k0 + cc];
    }
    __syncthreads();
    bf16x8 af[4], bfr[4];
#pragma unroll
    for (int mi = 0; mi < 4; mi++)
      af[mi] = *(const bf16x8*)&As[(wm + mi * 16 + l16) * 40 + quad * 8];
#pragma unroll
    for (int ni = 0; ni < 4; ni++)
      bfr[ni] = *(const bf16x8*)&Bs[(wn + ni * 16 + l16) * 40 + quad * 8];
#pragma unroll
    for (int mi = 0; mi < 4; mi++)
#pragma unroll
      for (int ni = 0; ni < 4; ni++)
        acc[mi][ni] = MFMA16(af[mi], bfr[ni], acc[mi][ni]);
    __syncthreads();
  }
#pragma unroll
  for (int mi = 0; mi < 4; mi++)
#pragma unroll
    for (int ni = 0; ni < 4; ni++)
#pragma unroll
      for (int r = 0; r < 4; r++)
        C[(size_t)(m0 + wm + mi * 16 + quad * 4 + r) * N + n0 + wn + ni * 16 + l16] =
            acc[mi][ni][r];
}

// ---------------- bias + rmsnorm + rope for Q,K: one wave per (slot, b, s) row ----------------
// rows: slot 0..15 = q heads, 16..17 = k kv-heads.  grid = 18*2048/4 blocks of 256.
__global__ __launch_bounds__(256) void qkv_post_kernel(
    const float* __restrict__ qkv, const float* __restrict__ qbias,
    const float* __restrict__ kbias, const float* __restrict__ qg,
    const float* __restrict__ kg, const float* __restrict__ cosb,
    const float* __restrict__ sinb, const float* __restrict__ maskp,
    short* __restrict__ qo, short* __restrict__ ko) {
  const int rid = blockIdx.x * 4 + (threadIdx.x >> 6);
  const int lane = threadIdx.x & 63;
  const int slot = rid >> 11;
  const int bs = rid & 2047;
  const int b = bs >> 10, s = bs & 1023;
  const float* row = qkv + (size_t)bs * 2560;
  int off;
  const float* bias;
  const float* gamma;
  if (slot < 16) { off = slot * 128; bias = qbias + slot * 128; gamma = qg; }
  else { off = 2048 + (slot - 16) * 128; bias = kbias + (slot - 16) * 128; gamma = kg; }
  float v0 = row[off + lane] + bias[lane];
  float v1 = row[off + 64 + lane] + bias[64 + lane];
  float ss = v0 * v0 + v1 * v1;
#pragma unroll
  for (int o = 1; o < 64; o <<= 1) ss += __shfl_xor(ss, o);
  float r = rsqrtf(ss * (1.0f / 128.0f) + 1e-6f);
  v0 = gamma[lane] * v0 * r;
  v1 = gamma[64 + lane] * v1 * r;
  // sectioned rope: SEC=(16,24,24) repeating with period 64 -> sel(d) == sel(d+64)
  int sel = (lane < 16) ? 0 : (lane < 40) ? 1 : 2;
  size_t ci = ((size_t)(sel * 2 + b) * 1024 + s) * 128 + lane;
  float c0 = cosb[ci], s0 = sinb[ci], c1 = cosb[ci + 64], s1 = sinb[ci + 64];
  float o0 = v0 * c0 - v1 * s0;   // d<64: partner = -v[d+64]
  float o1 = v1 * c1 + v0 * s1;   // d>=64: partner = +v[d-64]
  if (slot >= 16) { float mk = maskp[bs]; o0 *= mk; o1 *= mk; }
  size_t oidx;
  short* optr;
  if (slot < 16) { oidx = (((size_t)(b * 16 + slot) * 1024) + s) * 128; optr = qo; }
  else { oidx = (((size_t)(b * 2 + (slot - 16)) * 1024) + s) * 128; optr = ko; }
  optr[oidx + lane] = f2bf(o0);
  optr[oidx + 64 + lane] = f2bf(o1);
}

// ---------------- V: bias + mask + transpose (b,kv,s,d)->(b,kv,d,s), fp32->bf16 ----------------
__global__ __launch_bounds__(256) void vtrans_kernel(const float* __restrict__ qkv,
                                                     const float* __restrict__ vbias,
                                                     const float* __restrict__ maskp,
                                                     short* __restrict__ vtb) {
  __shared__ short t[32][33];
  const int bz = blockIdx.z;             // b*2+kv
  const int bq = bz >> 1, kv = bz & 1;
  const int d0 = blockIdx.x * 32, s0 = blockIdx.y * 32;
  const int tx = threadIdx.x & 31;
  const int ty = threadIdx.x >> 5;
#pragma unroll
  for (int i = 0; i < 4; i++) {
    int s = s0 + ty + i * 8;
    float val = qkv[((size_t)(bq * 1024 + s)) * 2560 + 2304 + kv * 128 + d0 + tx] +
                vbias[kv * 128 + d0 + tx];
    t[ty + i * 8][tx] = f2bf(val * maskp[bq * 1024 + s]);
  }
  __syncthreads();
#pragma unroll
  for (int i = 0; i < 4; i++)
    vtb[((size_t)bz * 128 + d0 + ty + i * 8) * 1024 + s0 + tx] = t[tx][ty + i * 8];
}

// ---------------- flash-style causal GQA attention, 64-key steps ----------------
// grid (S/64, NH, B), block 256 (4 waves); wave owns 16 q rows
__global__ __launch_bounds__(256) void attn_kernel(const short* __restrict__ Q,
                                                   const short* __restrict__ K,
                                                   const short* __restrict__ Vt_g,
                                                   short* __restrict__ Oo) {
  const int qt = blockIdx.x;
  const int h = blockIdx.y;
  const int b = blockIdx.z;
  const int kv = h >> 3;  // G = 8
  const int tid = threadIdx.x;
  const int wave = tid >> 6, lane = tid & 63;
  const int quad = lane >> 4, l16 = lane & 15;
  __shared__ __align__(16) short Ks[64 * 136];   // (key, d) pad 136
  __shared__ __align__(16) short Vs[128 * 72];   // (d, key) pad 72
  __shared__ __align__(16) short Ps[4][16 * 68]; // per-wave (row, key) pad 68

  const size_t qoff = (((size_t)(b * 16 + h) * 1024) + qt * 64 + wave * 16 + l16) * 128;
  bf16x8 aq[4];
#pragma unroll
  for (int kk = 0; kk < 4; kk++) aq[kk] = *(const bf16x8*)&Q[qoff + kk * 32 + quad * 8];

  f32x4 o[8];
#pragma unroll
  for (int i = 0; i < 8; i++) o[i] = (f32x4){0.f, 0.f, 0.f, 0.f};
  float m[4], l[4];
#pragma unroll
  for (int r = 0; r < 4; r++) { m[r] = -1e30f; l[r] = 0.f; }
  const int qrow0 = qt * 64 + wave * 16 + quad * 4;
  const size_t koff = ((size_t)(b * 2 + kv) * 1024) * 128;  // K: (bkv, s, d)
  const size_t voff = koff;                                  // Vt: (bkv, d, s)
  const int nsteps = qt + 1;
  const float scale = 0.08838834764831845f;  // 1/sqrt(128)

  for (int st = 0; st < nsteps; st++) {
    const int ks0 = st * 64;
#pragma unroll
    for (int it = 0; it < 4; it++) {
      int c = it * 256 + tid;
      {  // K tile: 64 rows x 128 shorts = 1024 16B chunks
        int row = c >> 4, cc = (c & 15) * 8;
        *(int4*)&Ks[row * 136 + cc] =
            *(const int4*)&K[koff + (size_t)(ks0 + row) * 128 + cc];
      }
      {  // V tile (pre-transposed): 128 d-rows x 64 shorts = 1024 16B chunks
        int d = c >> 3, cc = (c & 7) * 8;
        *(int4*)&Vs[d * 72 + cc] =
            *(const int4*)&Vt_g[voff + (size_t)d * 1024 + ks0 + cc];
      }
    }
    __syncthreads();
    // scores: S(16q x 64k)
    f32x4 sc[4];
#pragma unroll
    for (int nt = 0; nt < 4; nt++) sc[nt] = (f32x4){0.f, 0.f, 0.f, 0.f};
#pragma unroll
    for (int nt = 0; nt < 4; nt++)
#pragma unroll
      for (int kk = 0; kk < 4; kk++) {
        bf16x8 bk = *(const bf16x8*)&Ks[(nt * 16 + l16) * 136 + kk * 32 + quad * 8];
        sc[nt] = MFMA16(aq[kk], bk, sc[nt]);
      }
    float sv[4][4], mx[4];
#pragma unroll
    for (int r = 0; r < 4; r++) mx[r] = -1e30f;
#pragma unroll
    for (int nt = 0; nt < 4; nt++)
#pragma unroll
      for (int r = 0; r < 4; r++) {
        float s = sc[nt][r] * scale;
        int kcol = ks0 + nt * 16 + l16;
        if (kcol > qrow0 + r) s = -1e30f;  // causal
        sv[nt][r] = s;
        mx[r] = fmaxf(mx[r], s);
      }
#pragma unroll
    for (int off = 1; off < 16; off <<= 1)
#pragma unroll
      for (int r = 0; r < 4; r++) mx[r] = fmaxf(mx[r], __shfl_xor(mx[r], off));
    float alpha[4];
#pragma unroll
    for (int r = 0; r < 4; r++) {
      float mn = fmaxf(m[r], mx[r]);
      alpha[r] = __expf(m[r] - mn);
      m[r] = mn;
    }
    float rs[4] = {0.f, 0.f, 0.f, 0.f};  // per-lane partial row sum
#pragma unroll
    for (int nt = 0; nt < 4; nt++)
#pragma unroll
      for (int r = 0; r < 4; r++) {
        float p = __expf(sv[nt][r] - m[r]);
        sv[nt][r] = p;
        rs[r] += p;
      }
#pragma unroll
    for (int r = 0; r < 4; r++) l[r] = l[r] * alpha[r] + rs[r];
#pragma unroll
    for (int i = 0; i < 8; i++)
#pragma unroll
      for (int r = 0; r < 4; r++) o[i][r] *= alpha[r];
    // P: C-layout -> A-layout via per-wave LDS round-trip
    short* P = &Ps[wave][0];
#pragma unroll
    for (int nt = 0; nt < 4; nt++)
#pragma unroll
      for (int r = 0; r < 4; r++)
        P[(quad * 4 + r) * 68 + nt * 16 + l16] = f2bf(sv[nt][r]);
    __asm__ volatile("s_waitcnt lgkmcnt(0)" ::: "memory");
    bf16x8 pa0 = *(const bf16x8*)&P[l16 * 68 + quad * 8];
    bf16x8 pa1 = *(const bf16x8*)&P[l16 * 68 + 32 + quad * 8];
#pragma unroll
    for (int nt = 0; nt < 8; nt++) {
      bf16x8 bv0 = *(const bf16x8*)&Vs[(nt * 16 + l16) * 72 + quad * 8];
      bf16x8 bv1 = *(const bf16x8*)&Vs[(nt * 16 + l16) * 72 + 32 + quad * 8];
      o[nt] = MFMA16(pa0, bv0, o[nt]);
      o[nt] = MFMA16(pa1, bv1, o[nt]);
    }
    __syncthreads();
  }
  // reduce per-lane partial l across the 16 lanes of the row group
#pragma unroll
  for (int off = 1; off < 16; off <<= 1)
#pragma unroll
    for (int r = 0; r < 4; r++) l[r] += __shfl_xor(l[r], off);
#pragma unroll
  for (int r = 0; r < 4; r++) l[r] = 1.f / l[r];
#pragma unroll
  for (int nt = 0; nt < 8; nt++)
#pragma unroll
    for (int r = 0; r < 4; r++) {
      size_t idx = ((size_t)(b * 1024 + qrow0 + r)) * 2048 + h * 128 + nt * 16 + l16;
      Oo[idx] = f2bf(o[nt][r] * l[r]);
    }
}

extern "C" void kernel_launch(void* const* d_in, const int* in_sizes, int n_in,
                              void* d_out, int out_size, void* d_ws, size_t ws_size,
                              hipStream_t stream) {
  const float* x = (const float*)d_in[0];
  const float* cosb = (const float*)d_in[1];
  const float* sinb = (const float*)d_in[2];
  const float* mask = (const float*)d_in[3];
  const float* q_w = (const float*)d_in[4];
  const float* q_b = (const float*)d_in[5];
  const float* k_w = (const float*)d_in[6];
  const float* k_b = (const float*)d_in[7];
  const float* v_w = (const float*)d_in[8];
  const float* v_b = (const float*)d_in[9];
  const float* qg = (const float*)d_in[10];
  const float* kg = (const float*)d_in[11];
  const float* o_w = (const float*)d_in[12];
  float* out = (float*)d_out;

  char* ws = (char*)d_ws;
  // region A (0..8MB): xb, later reused as attention output
  short* xb = (short*)(ws);
  short* attn = xb;
  // region B (8..18MB): qkv weight N-major; front 1MB reused later as V^T
  short* wqkv_t = (short*)(ws + (size_t)(8u << 20));
  short* vtb = (short*)(ws + (size_t)(8u << 20));  // alive only after gemm #1
  // region C (18..38MB): fp32 qkv raw; front 8MB reused later as o_w^T
  float* qkv_raw = (float*)(ws + (size_t)(18u << 20));
  short* wo_t = (short*)(ws + (size_t)(18u << 20));
  // regions D/E
  short* qb = (short*)(ws + (size_t)(38u << 20));  // 8 MB  (B,NH,S,HD)
  short* kb = (short*)(ws + (size_t)(46u << 20));  // 1 MB  (B,NKV,S,HD)

  // 1. convert x -> bf16
  cvt_kernel<<<4096, 256, 0, stream>>>(x, xb, 2048 * 2048);
  // 2. transpose-convert weights into concatenated N-major (2560 x 2048)
  tconv_kernel<<<dim3(64, 64), 256, 0, stream>>>(q_w, wqkv_t, 2048, 2048);
  tconv_kernel<<<dim3(8, 64), 256, 0, stream>>>(k_w, wqkv_t + (size_t)2048 * 2048, 2048, 256);
  tconv_kernel<<<dim3(8, 64), 256, 0, stream>>>(v_w, wqkv_t + (size_t)2304 * 2048, 2048, 256);
  // 3. QKV GEMM: (2048 x 2560) fp32
  gemm_kernel<<<dim3(20, 16), 256, 0, stream>>>(xb, wqkv_t, qkv_raw, 2048, 2560, 2048);
  // 4. Q/K: bias + rmsnorm + rope (+mask for K)
  qkv_post_kernel<<<9216, 256, 0, stream>>>(qkv_raw, q_b, k_b, qg, kg, cosb, sinb, mask,
                                            qb, kb);
  // 5. V: bias + mask + transpose -> (b,kv,d,s) bf16
  vtrans_kernel<<<dim3(4, 32, 4), 256, 0, stream>>>(qkv_raw, v_b, mask, vtb);
  // 6. transpose o_w (qkv_raw fully consumed)
  tconv_kernel<<<dim3(64, 64), 256, 0, stream>>>(o_w, wo_t, 2048, 2048);
  // 7. attention
  attn_kernel<<<dim3(16, 16, 2), 256, 0, stream>>>(qb, kb, vtb, attn);
  // 8. output GEMM -> d_out fp32
  gemm_kernel<<<dim3(16, 16), 256, 0, stream>>>(attn, wo_t, out, 2048, 2048, 2048);
}

// Round 3
// 281.098 us; speedup vs baseline: 1.2913x; 1.1080x over previous
//
#include <hip/hip_runtime.h>

typedef __attribute__((ext_vector_type(8))) short bf16x8;
typedef __attribute__((ext_vector_type(4))) float f32x4;

#define MFMA16(a, b, c) __builtin_amdgcn_mfma_f32_16x16x32_bf16(a, b, c, 0, 0, 0)

__device__ inline short f2bf(float f) {
  union { float f; unsigned u; } v;
  v.f = f;
  unsigned r = v.u + 0x7FFF + ((v.u >> 16) & 1);
  return (short)(r >> 16);
}
__device__ inline float bf2f(short s) {
  union { unsigned u; float f; } v;
  v.u = ((unsigned)(unsigned short)s) << 16;
  return v.f;
}
#define GLD_LDS16(g, l)                                                        \
  __builtin_amdgcn_global_load_lds(                                            \
      (const __attribute__((address_space(1))) unsigned int*)(g),              \
      (__attribute__((address_space(3))) unsigned int*)(l), 16, 0, 0)

// ---------------- convert fp32 -> bf16 ----------------
__global__ __launch_bounds__(256) void cvt_kernel(const float* __restrict__ src,
                                                  short* __restrict__ dst, int n) {
  int i = (blockIdx.x * 256 + threadIdx.x) * 4;
  if (i >= n) return;
  float4 f = *(const float4*)&src[i];
  short4 o;
  o.x = f2bf(f.x); o.y = f2bf(f.y); o.z = f2bf(f.z); o.w = f2bf(f.w);
  *(short4*)&dst[i] = o;
}

// ---------------- transpose + convert: src (R x C) fp32 -> dst (C x R) bf16 ----------------
__global__ __launch_bounds__(256) void tconv_kernel(const float* __restrict__ src,
                                                    short* __restrict__ dst, int R, int C) {
  __shared__ float t[32][33];
  const int bx = blockIdx.x * 32;
  const int by = blockIdx.y * 32;
  const int tx = threadIdx.x & 31;
  const int ty = threadIdx.x >> 5;
#pragma unroll
  for (int i = 0; i < 4; i++)
    t[ty + i * 8][tx] = src[(size_t)(by + ty + i * 8) * C + bx + tx];
  __syncthreads();
#pragma unroll
  for (int i = 0; i < 4; i++)
    dst[(size_t)(bx + ty + i * 8) * R + by + tx] = f2bf(t[tx][ty + i * 8]);
}

// ---------------- bf16 GEMM with global_load_lds staging + optional split-K ----------------
// C(MxN fp32) = A(M x lda bf16) * B^T(N x ldb bf16); blockIdx.z picks K-half -> C0/C1
__global__ __launch_bounds__(256) void gemm_kernel(const short* __restrict__ A,
                                                   const short* __restrict__ B,
                                                   float* __restrict__ C0,
                                                   float* __restrict__ C1,
                                                   int lda, int ldb, int N, int Klen) {
  __shared__ __align__(16) short As[128 * 32];
  __shared__ __align__(16) short Bs[128 * 32];
  const int tid = threadIdx.x;
  const int lane = tid & 63, wave = tid >> 6;
  const int quad = lane >> 4, l16 = lane & 15;
  const int m0 = blockIdx.y * 128, n0 = blockIdx.x * 128;
  const int kz = blockIdx.z;
  const short* Ap = A + (size_t)kz * Klen;
  const short* Bp = B + (size_t)kz * Klen;
  float* C = kz ? C1 : C0;
  const int wm = (wave >> 1) * 64, wn = (wave & 1) * 64;
  f32x4 acc[4][4];
#pragma unroll
  for (int mi = 0; mi < 4; mi++)
#pragma unroll
    for (int ni = 0; ni < 4; ni++) acc[mi][ni] = (f32x4){0.f, 0.f, 0.f, 0.f};

  for (int k0 = 0; k0 < Klen; k0 += 32) {
#pragma unroll
    for (int it = 0; it < 2; it++) {
      int c = it * 256 + tid;            // 512 chunks of 16B per tile
      int row = c >> 2, cc = (c & 3) * 8;
      GLD_LDS16(&Ap[(size_t)(m0 + row) * lda + k0 + cc], &As[c * 8]);
      GLD_LDS16(&Bp[(size_t)(n0 + row) * ldb + k0 + cc], &Bs[c * 8]);
    }
    __syncthreads();
    bf16x8 af[4], bfr[4];
#pragma unroll
    for (int mi = 0; mi < 4; mi++)
      af[mi] = *(const bf16x8*)&As[(wm + mi * 16 + l16) * 32 + quad * 8];
#pragma unroll
    for (int ni = 0; ni < 4; ni++)
      bfr[ni] = *(const bf16x8*)&Bs[(wn + ni * 16 + l16) * 32 + quad * 8];
#pragma unroll
    for (int mi = 0; mi < 4; mi++)
#pragma unroll
      for (int ni = 0; ni < 4; ni++)
        acc[mi][ni] = MFMA16(af[mi], bfr[ni], acc[mi][ni]);
    __syncthreads();
  }
#pragma unroll
  for (int mi = 0; mi < 4; mi++)
#pragma unroll
    for (int ni = 0; ni < 4; ni++)
#pragma unroll
      for (int r = 0; r < 4; r++)
        C[(size_t)(m0 + wm + mi * 16 + quad * 4 + r) * N + n0 + wn + ni * 16 + l16] =
            acc[mi][ni][r];
}

// ---------------- out = out + part ----------------
__global__ __launch_bounds__(256) void addf_kernel(float* __restrict__ out,
                                                   const float* __restrict__ part) {
  int i = (blockIdx.x * 256 + threadIdx.x) * 4;
  float4 a = *(float4*)&out[i];
  float4 b = *(const float4*)&part[i];
  a.x += b.x; a.y += b.y; a.z += b.z; a.w += b.w;
  *(float4*)&out[i] = a;
}

// ---------------- bias + rmsnorm + rope for Q,K: one wave per row ----------------
__global__ __launch_bounds__(256) void qkv_post_kernel(
    const float* __restrict__ qkv, const float* __restrict__ qbias,
    const float* __restrict__ kbias, const float* __restrict__ qg,
    const float* __restrict__ kg, const float* __restrict__ cosb,
    const float* __restrict__ sinb, const float* __restrict__ maskp,
    short* __restrict__ qo, short* __restrict__ ko) {
  const int rid = blockIdx.x * 4 + (threadIdx.x >> 6);
  const int lane = threadIdx.x & 63;
  const int slot = rid >> 11;
  const int bs = rid & 2047;
  const int b = bs >> 10, s = bs & 1023;
  const float* row = qkv + (size_t)bs * 2560;
  int off;
  const float* bias;
  const float* gamma;
  if (slot < 16) { off = slot * 128; bias = qbias + slot * 128; gamma = qg; }
  else { off = 2048 + (slot - 16) * 128; bias = kbias + (slot - 16) * 128; gamma = kg; }
  float v0 = row[off + lane] + bias[lane];
  float v1 = row[off + 64 + lane] + bias[64 + lane];
  float ss = v0 * v0 + v1 * v1;
#pragma unroll
  for (int o = 1; o < 64; o <<= 1) ss += __shfl_xor(ss, o);
  float r = rsqrtf(ss * (1.0f / 128.0f) + 1e-6f);
  v0 = gamma[lane] * v0 * r;
  v1 = gamma[64 + lane] * v1 * r;
  int sel = (lane < 16) ? 0 : (lane < 40) ? 1 : 2;
  size_t ci = ((size_t)(sel * 2 + b) * 1024 + s) * 128 + lane;
  float c0 = cosb[ci], s0 = sinb[ci], c1 = cosb[ci + 64], s1 = sinb[ci + 64];
  float o0 = v0 * c0 - v1 * s0;
  float o1 = v1 * c1 + v0 * s1;
  if (slot >= 16) { float mk = maskp[bs]; o0 *= mk; o1 *= mk; }
  size_t oidx;
  short* optr;
  if (slot < 16) { oidx = (((size_t)(b * 16 + slot) * 1024) + s) * 128; optr = qo; }
  else { oidx = (((size_t)(b * 2 + (slot - 16)) * 1024) + s) * 128; optr = ko; }
  optr[oidx + lane] = f2bf(o0);
  optr[oidx + 64 + lane] = f2bf(o1);
}

// ---------------- V: bias + mask + transpose -> (b,kv,d,s) bf16 ----------------
__global__ __launch_bounds__(256) void vtrans_kernel(const float* __restrict__ qkv,
                                                     const float* __restrict__ vbias,
                                                     const float* __restrict__ maskp,
                                                     short* __restrict__ vtb) {
  __shared__ short t[32][33];
  const int bz = blockIdx.z;
  const int bq = bz >> 1, kv = bz & 1;
  const int d0 = blockIdx.x * 32, s0 = blockIdx.y * 32;
  const int tx = threadIdx.x & 31;
  const int ty = threadIdx.x >> 5;
#pragma unroll
  for (int i = 0; i < 4; i++) {
    int s = s0 + ty + i * 8;
    float val = qkv[((size_t)(bq * 1024 + s)) * 2560 + 2304 + kv * 128 + d0 + tx] +
                vbias[kv * 128 + d0 + tx];
    t[ty + i * 8][tx] = f2bf(val * maskp[bq * 1024 + s]);
  }
  __syncthreads();
#pragma unroll
  for (int i = 0; i < 4; i++)
    vtb[((size_t)bz * 128 + d0 + ty + i * 8) * 1024 + s0 + tx] = t[tx][ty + i * 8];
}

// ---------------- flash attention, key-chunk split (chunk = 256 keys, <=4 steps) ----------------
// grid (40, NH, B): x enumerates (qt, kc) with nchunks(qt) = qt/4+1
__global__ __launch_bounds__(256) void attn_kernel(const short* __restrict__ Q,
                                                   const short* __restrict__ K,
                                                   const short* __restrict__ Vt_g,
                                                   short* __restrict__ po,
                                                   float* __restrict__ pml) {
  int x = blockIdx.x;
  const int h = blockIdx.y;
  const int b = blockIdx.z;
  int g = 0, base = 0;
  while (x >= base + 4 * (g + 1)) { base += 4 * (g + 1); g++; }
  const int r0 = x - base;
  const int qt = 4 * g + r0 / (g + 1);
  const int kc = r0 % (g + 1);
  int nsteps = qt - 4 * kc + 1;
  if (nsteps > 4) nsteps = 4;

  const int kv = h >> 3;
  const int tid = threadIdx.x;
  const int wave = tid >> 6, lane = tid & 63;
  const int quad = lane >> 4, l16 = lane & 15;
  __shared__ __align__(16) short Ks[64 * 136];
  __shared__ __align__(16) short Vs[128 * 72];
  __shared__ __align__(16) short Ps[4][16 * 68];

  const size_t qoff = (((size_t)(b * 16 + h) * 1024) + qt * 64 + wave * 16 + l16) * 128;
  bf16x8 aq[4];
#pragma unroll
  for (int kk = 0; kk < 4; kk++) aq[kk] = *(const bf16x8*)&Q[qoff + kk * 32 + quad * 8];

  f32x4 o[8];
#pragma unroll
  for (int i = 0; i < 8; i++) o[i] = (f32x4){0.f, 0.f, 0.f, 0.f};
  float m[4], l[4];
#pragma unroll
  for (int r = 0; r < 4; r++) { m[r] = -1e30f; l[r] = 0.f; }
  const int qrow0 = qt * 64 + wave * 16 + quad * 4;
  const size_t koff = ((size_t)(b * 2 + kv) * 1024) * 128;
  const size_t voff = koff;
  const float scale = 0.08838834764831845f;

  for (int st = 0; st < nsteps; st++) {
    const int ks0 = kc * 256 + st * 64;
#pragma unroll
    for (int it = 0; it < 4; it++) {
      int c = it * 256 + tid;
      {
        int row = c >> 4, cc = (c & 15) * 8;
        *(int4*)&Ks[row * 136 + cc] =
            *(const int4*)&K[koff + (size_t)(ks0 + row) * 128 + cc];
      }
      {
        int d = c >> 3, cc = (c & 7) * 8;
        *(int4*)&Vs[d * 72 + cc] =
            *(const int4*)&Vt_g[voff + (size_t)d * 1024 + ks0 + cc];
      }
    }
    __syncthreads();
    f32x4 sc[4];
#pragma unroll
    for (int nt = 0; nt < 4; nt++) sc[nt] = (f32x4){0.f, 0.f, 0.f, 0.f};
#pragma unroll
    for (int nt = 0; nt < 4; nt++)
#pragma unroll
      for (int kk = 0; kk < 4; kk++) {
        bf16x8 bk = *(const bf16x8*)&Ks[(nt * 16 + l16) * 136 + kk * 32 + quad * 8];
        sc[nt] = MFMA16(aq[kk], bk, sc[nt]);
      }
    float sv[4][4], mx[4];
#pragma unroll
    for (int r = 0; r < 4; r++) mx[r] = -1e30f;
#pragma unroll
    for (int nt = 0; nt < 4; nt++)
#pragma unroll
      for (int r = 0; r < 4; r++) {
        float s = sc[nt][r] * scale;
        int kcol = ks0 + nt * 16 + l16;
        if (kcol > qrow0 + r) s = -1e30f;
        sv[nt][r] = s;
        mx[r] = fmaxf(mx[r], s);
      }
#pragma unroll
    for (int off = 1; off < 16; off <<= 1)
#pragma unroll
      for (int r = 0; r < 4; r++) mx[r] = fmaxf(mx[r], __shfl_xor(mx[r], off));
    float alpha[4];
#pragma unroll
    for (int r = 0; r < 4; r++) {
      float mn = fmaxf(m[r], mx[r]);
      alpha[r] = __expf(m[r] - mn);
      m[r] = mn;
    }
    float rs[4] = {0.f, 0.f, 0.f, 0.f};
#pragma unroll
    for (int nt = 0; nt < 4; nt++)
#pragma unroll
      for (int r = 0; r < 4; r++) {
        float p = __expf(sv[nt][r] - m[r]);
        sv[nt][r] = p;
        rs[r] += p;
      }
#pragma unroll
    for (int r = 0; r < 4; r++) l[r] = l[r] * alpha[r] + rs[r];
#pragma unroll
    for (int i = 0; i < 8; i++)
#pragma unroll
      for (int r = 0; r < 4; r++) o[i][r] *= alpha[r];
    short* P = &Ps[wave][0];
#pragma unroll
    for (int nt = 0; nt < 4; nt++)
#pragma unroll
      for (int r = 0; r < 4; r++)
        P[(quad * 4 + r) * 68 + nt * 16 + l16] = f2bf(sv[nt][r]);
    __asm__ volatile("s_waitcnt lgkmcnt(0)" ::: "memory");
    bf16x8 pa0 = *(const bf16x8*)&P[l16 * 68 + quad * 8];
    bf16x8 pa1 = *(const bf16x8*)&P[l16 * 68 + 32 + quad * 8];
#pragma unroll
    for (int nt = 0; nt < 8; nt++) {
      bf16x8 bv0 = *(const bf16x8*)&Vs[(nt * 16 + l16) * 72 + quad * 8];
      bf16x8 bv1 = *(const bf16x8*)&Vs[(nt * 16 + l16) * 72 + 32 + quad * 8];
      o[nt] = MFMA16(pa0, bv0, o[nt]);
      o[nt] = MFMA16(pa1, bv1, o[nt]);
    }
    __syncthreads();
  }
#pragma unroll
  for (int off = 1; off < 16; off <<= 1)
#pragma unroll
    for (int r = 0; r < 4; r++) l[r] += __shfl_xor(l[r], off);
  const int p = (b * 16 + h) * 40 + blockIdx.x;
  const int lrow = wave * 16 + quad * 4;
#pragma unroll
  for (int nt = 0; nt < 8; nt++)
#pragma unroll
    for (int r = 0; r < 4; r++)
      po[(size_t)p * 8192 + (size_t)(lrow + r) * 128 + nt * 16 + l16] = f2bf(o[nt][r]);
  if (l16 == 0) {
#pragma unroll
    for (int r = 0; r < 4; r++) {
      pml[(size_t)p * 128 + lrow + r] = m[r];
      pml[(size_t)p * 128 + 64 + lrow + r] = l[r];
    }
  }
}

// ---------------- combine partials -> attn output (b*S, NH*HD) bf16 ----------------
__global__ __launch_bounds__(256) void attn_combine_kernel(const short* __restrict__ po,
                                                           const float* __restrict__ pml,
                                                           short* __restrict__ attn) {
  const int qt = blockIdx.x, h = blockIdx.y, b = blockIdx.z;
  const int g = qt >> 2, nc = g + 1;
  const int x0 = 2 * g * (g + 1) + (qt & 3) * nc;
  const int row = threadIdx.x >> 2;
  const int d0 = (threadIdx.x & 3) * 32;
  const int pbase = (b * 16 + h) * 40 + x0;
  float mm[4], ll[4], M = -1e30f;
#pragma unroll
  for (int kc = 0; kc < 4; kc++)
    if (kc < nc) {
      mm[kc] = pml[(size_t)(pbase + kc) * 128 + row];
      ll[kc] = pml[(size_t)(pbase + kc) * 128 + 64 + row];
      M = fmaxf(M, mm[kc]);
    }
  float denom = 0.f, sc[4];
#pragma unroll
  for (int kc = 0; kc < 4; kc++)
    if (kc < nc) { sc[kc] = __expf(mm[kc] - M); denom += sc[kc] * ll[kc]; }
  float inv = 1.f / denom;
  float acc[32];
#pragma unroll
  for (int j = 0; j < 32; j++) acc[j] = 0.f;
#pragma unroll
  for (int kc = 0; kc < 4; kc++)
    if (kc < nc) {
      const short* src = po + (size_t)(pbase + kc) * 8192 + (size_t)row * 128 + d0;
#pragma unroll
      for (int j = 0; j < 4; j++) {
        int4 v = *(const int4*)&src[j * 8];
        const short* vs = (const short*)&v;
#pragma unroll
        for (int e = 0; e < 8; e++) acc[j * 8 + e] += sc[kc] * bf2f(vs[e]);
      }
    }
  short ob[32];
#pragma unroll
  for (int j = 0; j < 32; j++) ob[j] = f2bf(acc[j] * inv);
  short* dst = attn + ((size_t)(b * 1024 + qt * 64 + row)) * 2048 + h * 128 + d0;
#pragma unroll
  for (int j = 0; j < 4; j++) *(int4*)&dst[j * 8] = *(const int4*)&ob[j * 8];
}

extern "C" void kernel_launch(void* const* d_in, const int* in_sizes, int n_in,
                              void* d_out, int out_size, void* d_ws, size_t ws_size,
                              hipStream_t stream) {
  const float* x = (const float*)d_in[0];
  const float* cosb = (const float*)d_in[1];
  const float* sinb = (const float*)d_in[2];
  const float* mask = (const float*)d_in[3];
  const float* q_w = (const float*)d_in[4];
  const float* q_b = (const float*)d_in[5];
  const float* k_w = (const float*)d_in[6];
  const float* k_b = (const float*)d_in[7];
  const float* v_w = (const float*)d_in[8];
  const float* v_b = (const float*)d_in[9];
  const float* qg = (const float*)d_in[10];
  const float* kg = (const float*)d_in[11];
  const float* o_w = (const float*)d_in[12];
  float* out = (float*)d_out;

  char* ws = (char*)d_ws;
  // timeline-overlapped regions (48 MB total):
  short* xb = (short*)(ws);                          // 0..8   x bf16; later attn out
  short* attn = xb;
  short* wqkv_t = (short*)(ws + (size_t)(8u << 20)); // 8..18  weights (dead after gemm1)
  short* qb = (short*)(ws + (size_t)(8u << 20));     // 8..16  Q bf16 (after gemm1)
  short* kb = (short*)(ws + (size_t)(16u << 20));    // 16..17 K bf16
  short* vtb = (short*)(ws + (size_t)(17u << 20));   // 17..18 V^T bf16
  float* qkv_raw = (float*)(ws + (size_t)(18u << 20)); // 18..38 fp32 (dead after post)
  short* wo_t = (short*)(ws + (size_t)(18u << 20));  // 18..26 o_w^T
  short* po = (short*)(ws + (size_t)(26u << 20));    // 26..46 attn partials (bf16)
  float* pB = (float*)(ws + (size_t)(26u << 20));    // 26..42 out-gemm split-K partial
  float* pml = (float*)(ws + (size_t)(46u << 20));   // 46..46.7 partial m/l

  cvt_kernel<<<4096, 256, 0, stream>>>(x, xb, 2048 * 2048);
  tconv_kernel<<<dim3(64, 64), 256, 0, stream>>>(q_w, wqkv_t, 2048, 2048);
  tconv_kernel<<<dim3(8, 64), 256, 0, stream>>>(k_w, wqkv_t + (size_t)2048 * 2048, 2048, 256);
  tconv_kernel<<<dim3(8, 64), 256, 0, stream>>>(v_w, wqkv_t + (size_t)2304 * 2048, 2048, 256);
  gemm_kernel<<<dim3(20, 16, 1), 256, 0, stream>>>(xb, wqkv_t, qkv_raw, nullptr, 2048, 2048,
                                                   2560, 2048);
  qkv_post_kernel<<<9216, 256, 0, stream>>>(qkv_raw, q_b, k_b, qg, kg, cosb, sinb, mask,
                                            qb, kb);
  vtrans_kernel<<<dim3(4, 32, 4), 256, 0, stream>>>(qkv_raw, v_b, mask, vtb);
  tconv_kernel<<<dim3(64, 64), 256, 0, stream>>>(o_w, wo_t, 2048, 2048);
  attn_kernel<<<dim3(40, 16, 2), 256, 0, stream>>>(qb, kb, vtb, po, pml);
  attn_combine_kernel<<<dim3(16, 16, 2), 256, 0, stream>>>(po, pml, attn);
  gemm_kernel<<<dim3(16, 16, 2), 256, 0, stream>>>(attn, wo_t, out, pB, 2048, 2048, 2048,
                                                   1024);
  addf_kernel<<<4096, 256, 0, stream>>>(out, pB);
}